// Round 2
// baseline (1486.830 us; speedup 1.0000x reference)
//
#include <hip/hip_runtime.h>

#define B_  32
#define C_  1024
#define N_  1024
#define C8_ 128

// ---------------------------------------------------------------------------
// proj: P[b][o][n] = sum_c W[o][c] * x[b][c][n] + bias[o]   (bias folded in)
// Standard 64x64 fp32 tile GEMM, A staged transposed (pad +4 keeps float4 align)
// ---------------------------------------------------------------------------
template <int MO>
__global__ __launch_bounds__(256) void proj_kernel(
    const float* __restrict__ W, const float* __restrict__ bias,
    const float* __restrict__ xf, float* __restrict__ P)
{
    constexpr int BM = 64, BN = 64, BK = 16;
    constexpr int MT = MO / BM, NT = N_ / BN;
    int bid = blockIdx.x;
    int b   = bid / (MT * NT);
    int rr  = bid % (MT * NT);
    int m0  = (rr / NT) * BM;
    int n0  = (rr % NT) * BN;

    __shared__ float As[BK][BM + 4];   // [k][m], +4 pad keeps float4 alignment
    __shared__ float Bs[BK][BN];       // [k][n]

    int t  = threadIdx.x;
    int tx = t & 15, ty = t >> 4;
    int arow = t >> 2, acol = (t & 3) * 4;   // A tile: 64 rows x 16 k
    int brow = t >> 4, bcol = (t & 15) * 4;  // B tile: 16 k x 64 n

    float acc[4][4] = {};
    const float* xb = xf + (size_t)b * C_ * N_;

    for (int k0 = 0; k0 < C_; k0 += BK) {
        float4 a4 = *(const float4*)(W  + (size_t)(m0 + arow) * C_ + k0 + acol);
        float4 b4 = *(const float4*)(xb + (size_t)(k0 + brow) * N_ + n0 + bcol);
        __syncthreads();
        As[acol + 0][arow] = a4.x;
        As[acol + 1][arow] = a4.y;
        As[acol + 2][arow] = a4.z;
        As[acol + 3][arow] = a4.w;
        *(float4*)&Bs[brow][bcol] = b4;
        __syncthreads();
#pragma unroll
        for (int kk = 0; kk < BK; ++kk) {
            float a[4], bb[4];
#pragma unroll
            for (int i = 0; i < 4; ++i) a[i] = As[kk][ty * 4 + i];
#pragma unroll
            for (int j = 0; j < 4; ++j) bb[j] = Bs[kk][tx * 4 + j];
#pragma unroll
            for (int i = 0; i < 4; ++i)
#pragma unroll
                for (int j = 0; j < 4; ++j) acc[i][j] += a[i] * bb[j];
        }
    }

    float* Pb = P + (size_t)b * MO * N_;
#pragma unroll
    for (int i = 0; i < 4; ++i) {
        int m = m0 + ty * 4 + i;
        float bm = bias[m];
        float4 o = make_float4(acc[i][0] + bm, acc[i][1] + bm,
                               acc[i][2] + bm, acc[i][3] + bm);
        *(float4*)(Pb + (size_t)m * N_ + n0 + tx * 4) = o;
    }
}

// ---------------------------------------------------------------------------
// energy: E[b][r][m] = sum_o Q[b][o][r] * K[b][o][m]
// Both operands K-major -> both tiles load fully coalesced, no transpose.
// ---------------------------------------------------------------------------
__global__ __launch_bounds__(256) void energy_kernel(
    const float* __restrict__ Q, const float* __restrict__ K,
    float* __restrict__ att)
{
    constexpr int BM = 64, BN = 64, BK = 16;
    constexpr int T = N_ / BM;   // 16
    int bid = blockIdx.x;
    int b  = bid / (T * T);
    int rr = bid % (T * T);
    int r0 = (rr / T) * BM;      // energy row tile (n)
    int c0 = (rr % T) * BN;      // energy col tile (m)

    __shared__ float As[BK][BM]; // [o][r]
    __shared__ float Bs[BK][BN]; // [o][m]

    int t  = threadIdx.x;
    int tx = t & 15, ty = t >> 4;
    int lrow = t >> 4, lcol = (t & 15) * 4;

    float acc[4][4] = {};
    const float* Qb = Q + (size_t)b * C8_ * N_;
    const float* Kb = K + (size_t)b * C8_ * N_;

    for (int k0 = 0; k0 < C8_; k0 += BK) {
        float4 a4 = *(const float4*)(Qb + (size_t)(k0 + lrow) * N_ + r0 + lcol);
        float4 b4 = *(const float4*)(Kb + (size_t)(k0 + lrow) * N_ + c0 + lcol);
        __syncthreads();
        *(float4*)&As[lrow][lcol] = a4;
        *(float4*)&Bs[lrow][lcol] = b4;
        __syncthreads();
#pragma unroll
        for (int kk = 0; kk < BK; ++kk) {
            float a[4], bb[4];
#pragma unroll
            for (int i = 0; i < 4; ++i) a[i] = As[kk][ty * 4 + i];
#pragma unroll
            for (int j = 0; j < 4; ++j) bb[j] = Bs[kk][tx * 4 + j];
#pragma unroll
            for (int i = 0; i < 4; ++i)
#pragma unroll
                for (int j = 0; j < 4; ++j) acc[i][j] += a[i] * bb[j];
        }
    }

    float* ab = att + (size_t)b * N_ * N_;
#pragma unroll
    for (int i = 0; i < 4; ++i) {
        *(float4*)(ab + (size_t)(r0 + ty * 4 + i) * N_ + c0 + tx * 4) =
            make_float4(acc[i][0], acc[i][1], acc[i][2], acc[i][3]);
    }
}

// ---------------------------------------------------------------------------
// softmax over last dim, in place. One block (256 thr) per row of 1024.
// ---------------------------------------------------------------------------
__global__ __launch_bounds__(256) void softmax_kernel(float* __restrict__ att)
{
    size_t row = blockIdx.x;
    float* p = att + row * (size_t)N_;
    int t = threadIdx.x;

    float4 v = reinterpret_cast<float4*>(p)[t];
    float m = fmaxf(fmaxf(v.x, v.y), fmaxf(v.z, v.w));
#pragma unroll
    for (int off = 32; off; off >>= 1) m = fmaxf(m, __shfl_xor(m, off));

    __shared__ float redm[4];
    __shared__ float reds[4];
    int wave = t >> 6, lane = t & 63;
    if (lane == 0) redm[wave] = m;
    __syncthreads();
    m = fmaxf(fmaxf(redm[0], redm[1]), fmaxf(redm[2], redm[3]));

    float e0 = __expf(v.x - m), e1 = __expf(v.y - m);
    float e2 = __expf(v.z - m), e3 = __expf(v.w - m);
    float s = e0 + e1 + e2 + e3;
#pragma unroll
    for (int off = 32; off; off >>= 1) s += __shfl_xor(s, off);
    if (lane == 0) reds[wave] = s;
    __syncthreads();
    s = reds[0] + reds[1] + reds[2] + reds[3];

    float inv = 1.0f / s;
    reinterpret_cast<float4*>(p)[t] = make_float4(e0 * inv, e1 * inv, e2 * inv, e3 * inv);
}

// ---------------------------------------------------------------------------
// v_epi: V = Wv @ x_b + bv fused with epilogue
//   out[b][c][n] = gamma * (V[c][n] * att[b][n][c]) + x[b][c][n]
// att tile read coalesced ([n][c] contiguous in c... wait, att is [n][m] with
// m=n-index; we read rows n0..n0+63, cols m0..m0+63, contiguous in col) and
// transposed through padded LDS.
// ---------------------------------------------------------------------------
__global__ __launch_bounds__(256) void v_epi_kernel(
    const float* __restrict__ Wv, const float* __restrict__ bv,
    const float* __restrict__ xf, const float* __restrict__ att,
    const float* __restrict__ gamma, float* __restrict__ out)
{
    constexpr int BM = 64, BN = 64, BK = 16;
    constexpr int T = 16;
    int bid = blockIdx.x;
    int b  = bid / (T * T);
    int rr = bid % (T * T);
    int m0 = (rr / T) * BM;   // c tile (rows of V)
    int n0 = (rr % T) * BN;   // n tile (cols of V)

    __shared__ float As[BK][BM + 4];
    __shared__ float Bs[BK][BN];
    __shared__ float attS[BN][BM + 4];   // [n_local][c_local]

    int t  = threadIdx.x;
    int tx = t & 15, ty = t >> 4;
    int arow = t >> 2, acol = (t & 3) * 4;
    int brow = t >> 4, bcol = (t & 15) * 4;

    float acc[4][4] = {};
    const float* xb = xf + (size_t)b * C_ * N_;

    for (int k0 = 0; k0 < C_; k0 += BK) {
        float4 a4 = *(const float4*)(Wv + (size_t)(m0 + arow) * C_ + k0 + acol);
        float4 b4 = *(const float4*)(xb + (size_t)(k0 + brow) * N_ + n0 + bcol);
        __syncthreads();
        As[acol + 0][arow] = a4.x;
        As[acol + 1][arow] = a4.y;
        As[acol + 2][arow] = a4.z;
        As[acol + 3][arow] = a4.w;
        *(float4*)&Bs[brow][bcol] = b4;
        __syncthreads();
#pragma unroll
        for (int kk = 0; kk < BK; ++kk) {
            float a[4], bb[4];
#pragma unroll
            for (int i = 0; i < 4; ++i) a[i] = As[kk][ty * 4 + i];
#pragma unroll
            for (int j = 0; j < 4; ++j) bb[j] = Bs[kk][tx * 4 + j];
#pragma unroll
            for (int i = 0; i < 4; ++i)
#pragma unroll
                for (int j = 0; j < 4; ++j) acc[i][j] += a[i] * bb[j];
        }
    }

    // stage att tile: attS[n_local][c_local] = att[b][n0+n_local][m0+c_local]
    const float* ab = att + (size_t)b * N_ * N_;
#pragma unroll
    for (int rr2 = 0; rr2 < 4; ++rr2) {
        int row = (t >> 4) + rr2 * 16;    // 0..63
        int col = (t & 15) * 4;
        *(float4*)&attS[row][col] =
            *(const float4*)(ab + (size_t)(n0 + row) * N_ + m0 + col);
    }
    __syncthreads();

    float g = gamma[0];
    float* ob = out + (size_t)b * C_ * N_;
#pragma unroll
    for (int i = 0; i < 4; ++i) {
        int c = m0 + ty * 4 + i;
        float bvc = bv[c];
        float4 xv = *(const float4*)(xb + (size_t)c * N_ + n0 + tx * 4);
        float4 o;
        o.x = g * ((acc[i][0] + bvc) * attS[tx * 4 + 0][ty * 4 + i]) + xv.x;
        o.y = g * ((acc[i][1] + bvc) * attS[tx * 4 + 1][ty * 4 + i]) + xv.y;
        o.z = g * ((acc[i][2] + bvc) * attS[tx * 4 + 2][ty * 4 + i]) + xv.z;
        o.w = g * ((acc[i][3] + bvc) * attS[tx * 4 + 3][ty * 4 + i]) + xv.w;
        *(float4*)(ob + (size_t)c * N_ + n0 + tx * 4) = o;
    }
}

// ---------------------------------------------------------------------------
extern "C" void kernel_launch(void* const* d_in, const int* in_sizes, int n_in,
                              void* d_out, int out_size, void* d_ws, size_t ws_size,
                              hipStream_t stream)
{
    const float* x     = (const float*)d_in[0];
    const float* Wq    = (const float*)d_in[1];
    const float* bq    = (const float*)d_in[2];
    const float* Wk    = (const float*)d_in[3];
    const float* bk    = (const float*)d_in[4];
    const float* Wv    = (const float*)d_in[5];
    const float* bv    = (const float*)d_in[6];
    const float* gamma = (const float*)d_in[7];
    float* out = (float*)d_out;

    char* ws = (char*)d_ws;
    float* Q   = (float*)ws;                            // 16 MiB  (B*128*N f32)
    float* K   = (float*)(ws + ((size_t)16 << 20));     // 16 MiB
    float* att = (float*)(ws + ((size_t)32 << 20));     // 128 MiB (B*N*N f32)

    // Q/K projections (bias folded)
    proj_kernel<C8_><<<B_ * 2 * 16, 256, 0, stream>>>(Wq, bq, x, Q);
    proj_kernel<C8_><<<B_ * 2 * 16, 256, 0, stream>>>(Wk, bk, x, K);

    // energy = (Q+bq)^T (K+bk), per batch
    energy_kernel<<<B_ * 16 * 16, 256, 0, stream>>>(Q, K, att);

    // row softmax in place
    softmax_kernel<<<B_ * N_, 256, 0, stream>>>(att);

    // V GEMM + fused elementwise epilogue
    v_epi_kernel<<<B_ * 16 * 16, 256, 0, stream>>>(Wv, bv, x, att, gamma, out);
}

// Round 3
// 496.319 us; speedup vs baseline: 2.9957x; 2.9957x over previous
//
#include <hip/hip_runtime.h>

#define B_  32
#define C_  1024
#define N_  1024
#define C8_ 128

typedef unsigned short u16;
typedef __attribute__((ext_vector_type(8))) short short8v;
typedef __attribute__((ext_vector_type(4))) float f32x4;

__device__ __forceinline__ u16 f2bf(float f) {
    unsigned int u = __float_as_uint(f);
    u += 0x7fffu + ((u >> 16) & 1u);          // RNE
    return (u16)(u >> 16);
}
__device__ __forceinline__ float bf2f(u16 h) {
    return __uint_as_float(((unsigned int)h) << 16);
}

// ---------------------------------------------------------------------------
// fp32 -> bf16 elementwise (weights)
// ---------------------------------------------------------------------------
__global__ __launch_bounds__(256) void cvt_f32_bf16(
    const float* __restrict__ s, u16* __restrict__ d, int n)
{
    int i = (blockIdx.x * 256 + threadIdx.x) * 4;
    if (i >= n) return;
    float4 v = *(const float4*)(s + i);
    ushort4 o;
    o.x = f2bf(v.x); o.y = f2bf(v.y); o.z = f2bf(v.z); o.w = f2bf(v.w);
    *(ushort4*)(d + i) = o;
}

// ---------------------------------------------------------------------------
// x[b][c][n] fp32  ->  xt[b][n][c] bf16   (64x64 tiles via LDS)
// ---------------------------------------------------------------------------
__global__ __launch_bounds__(256) void transpose_x(
    const float* __restrict__ x, u16* __restrict__ xt)
{
    int bid = blockIdx.x;
    int b  = bid >> 8;
    int rr = bid & 255;
    int c0 = (rr >> 4) * 64;
    int n0 = (rr & 15) * 64;
    __shared__ u16 T[64][72];
    const float* xb = x + (size_t)b * C_ * N_;
    int t = threadIdx.x;
    int r = t >> 4, c4 = (t & 15) * 4;
#pragma unroll
    for (int i = 0; i < 4; ++i) {
        int row = r + i * 16;  // c_local
        float4 v = *(const float4*)(xb + (size_t)(c0 + row) * N_ + n0 + c4);
        T[c4 + 0][row] = f2bf(v.x);
        T[c4 + 1][row] = f2bf(v.y);
        T[c4 + 2][row] = f2bf(v.z);
        T[c4 + 3][row] = f2bf(v.w);
    }
    __syncthreads();
    u16* xtb = xt + (size_t)b * N_ * C_;
#pragma unroll
    for (int i = 0; i < 2; ++i) {
        int idx = t + i * 256;
        int row = idx >> 3, c8 = (idx & 7) * 8;   // n_local, c_local base
        uint2 lo = *(const uint2*)&T[row][c8];
        uint2 hi = *(const uint2*)&T[row][c8 + 4];
        u16* dp = xtb + (size_t)(n0 + row) * C_ + c0 + c8;
        *(uint2*)dp = lo;
        *(uint2*)(dp + 4) = hi;
    }
}

// ---------------------------------------------------------------------------
// Shared MFMA helpers: 128x128 tile, BK=32, 4 waves (2x2) of 64x64.
// LDS tiles [128][56] (pad->stride 112B: 16B-aligned b128 reads, ~2-way banks)
// Frag recipe (m92/m97-verified): a[e]=A[l&15][(l>>4)*8+e] (K-contig),
// b same from [n][k] tile; D: row=(l>>4)*4+r, col=l&15.
// ---------------------------------------------------------------------------
__device__ __forceinline__ void stage_tile(
    const u16* __restrict__ src, int k0, int rowStride, u16 (*dst)[56], int t)
{
#pragma unroll
    for (int i = 0; i < 2; ++i) {
        int idx = t + i * 256;
        int row = idx >> 2, q = idx & 3;
        uint4 v = *(const uint4*)(src + (size_t)row * rowStride + k0 + q * 8);
        *(uint4*)&dst[row][q * 8] = v;
    }
}

#define MFMA_CORE(As, Bs, acc, wm, wn, lm, kg)                                  \
    {                                                                           \
        short8v af[4], bf[4];                                                   \
        _Pragma("unroll")                                                       \
        for (int fi = 0; fi < 4; ++fi)                                          \
            af[fi] = *(const short8v*)&As[(wm)*64 + fi*16 + (lm)][kg];          \
        _Pragma("unroll")                                                       \
        for (int fj = 0; fj < 4; ++fj)                                          \
            bf[fj] = *(const short8v*)&Bs[(wn)*64 + fj*16 + (lm)][kg];          \
        _Pragma("unroll")                                                       \
        for (int fi = 0; fi < 4; ++fi)                                          \
            _Pragma("unroll")                                                   \
            for (int fj = 0; fj < 4; ++fj)                                      \
                acc[fi][fj] = __builtin_amdgcn_mfma_f32_16x16x32_bf16(          \
                    af[fi], bf[fj], acc[fi][fj], 0, 0, 0);                      \
    }

// ---------------------------------------------------------------------------
// proj: Qt/Kt[b][n][o] = bf16( W[o][:] . xt[b][n][:] + bias[o] )
// One launch handles both Q (mt=0) and K (mt=1).
// ---------------------------------------------------------------------------
__global__ __launch_bounds__(256) void proj_mfma(
    const u16* __restrict__ Wqb, const u16* __restrict__ Wkb,
    const float* __restrict__ bq, const float* __restrict__ bk,
    const u16* __restrict__ xt, u16* __restrict__ Qt, u16* __restrict__ Kt)
{
    int bid = blockIdx.x;              // b*16 + mt*8 + nt
    int b  = bid >> 4;
    int mt = (bid >> 3) & 1;
    int n0 = (bid & 7) * 128;
    const u16* W     = mt ? Wkb : Wqb;
    const float* bia = mt ? bk  : bq;
    u16* P           = mt ? Kt  : Qt;

    __shared__ u16 As[128][56], Bs[128][56];
    const u16* xb = xt + (size_t)b * N_ * C_ + (size_t)n0 * C_;

    int t = threadIdx.x, lane = t & 63, wid = t >> 6;
    int wm = wid >> 1, wn = wid & 1;
    int lm = lane & 15, l4 = lane >> 4, kg = l4 * 8;

    f32x4 acc[4][4] = {};
    for (int k0 = 0; k0 < C_; k0 += 32) {
        __syncthreads();
        stage_tile(W,  k0, C_, As, t);
        stage_tile(xb, k0, C_, Bs, t);
        __syncthreads();
        MFMA_CORE(As, Bs, acc, wm, wn, lm, kg);
    }

    u16* Pb = P + (size_t)b * N_ * C8_;
#pragma unroll
    for (int fi = 0; fi < 4; ++fi) {
        int ob = wm * 64 + fi * 16 + l4 * 4;
        float4 b4 = *(const float4*)(bia + ob);
#pragma unroll
        for (int fj = 0; fj < 4; ++fj) {
            int n = n0 + wn * 64 + fj * 16 + lm;
            ushort4 st;
            st.x = f2bf(acc[fi][fj][0] + b4.x);
            st.y = f2bf(acc[fi][fj][1] + b4.y);
            st.z = f2bf(acc[fi][fj][2] + b4.z);
            st.w = f2bf(acc[fi][fj][3] + b4.w);
            *(ushort4*)(Pb + (size_t)n * C8_ + ob) = st;
        }
    }
}

// ---------------------------------------------------------------------------
// energy: E[b][r][m] = Qt[b][r][:] . Kt[b][m][:]   (K = 128), bf16 out
// ---------------------------------------------------------------------------
__global__ __launch_bounds__(256) void energy_mfma(
    const u16* __restrict__ Qt, const u16* __restrict__ Kt,
    u16* __restrict__ att)
{
    int bid = blockIdx.x;              // b*64 + rt*8 + ct
    int b  = bid >> 6;
    int r0 = ((bid >> 3) & 7) * 128;
    int c0 = (bid & 7) * 128;

    __shared__ u16 As[128][56], Bs[128][56];
    const u16* Qb = Qt + (size_t)b * N_ * C8_ + (size_t)r0 * C8_;
    const u16* Kb = Kt + (size_t)b * N_ * C8_ + (size_t)c0 * C8_;

    int t = threadIdx.x, lane = t & 63, wid = t >> 6;
    int wm = wid >> 1, wn = wid & 1;
    int lm = lane & 15, l4 = lane >> 4, kg = l4 * 8;

    f32x4 acc[4][4] = {};
    for (int k0 = 0; k0 < C8_; k0 += 32) {
        __syncthreads();
        stage_tile(Qb, k0, C8_, As, t);
        stage_tile(Kb, k0, C8_, Bs, t);
        __syncthreads();
        MFMA_CORE(As, Bs, acc, wm, wn, lm, kg);
    }

    u16* Eb = att + (size_t)b * N_ * N_;
#pragma unroll
    for (int fi = 0; fi < 4; ++fi)
#pragma unroll
        for (int fj = 0; fj < 4; ++fj) {
            int mm = c0 + wn * 64 + fj * 16 + lm;
#pragma unroll
            for (int r = 0; r < 4; ++r) {
                int rr = r0 + wm * 64 + fi * 16 + l4 * 4 + r;
                Eb[(size_t)rr * N_ + mm] = f2bf(acc[fi][fj][r]);
            }
        }
}

// ---------------------------------------------------------------------------
// softmax over last dim, bf16 in place. Block = one row of 1024.
// ---------------------------------------------------------------------------
__global__ __launch_bounds__(256) void softmax_bf16(u16* __restrict__ att)
{
    size_t row = blockIdx.x;
    u16* p = att + row * N_;
    int t = threadIdx.x;

    uint2 w = *(const uint2*)(p + t * 4);
    float v0 = bf2f((u16)(w.x & 0xffff)), v1 = bf2f((u16)(w.x >> 16));
    float v2 = bf2f((u16)(w.y & 0xffff)), v3 = bf2f((u16)(w.y >> 16));

    float m = fmaxf(fmaxf(v0, v1), fmaxf(v2, v3));
#pragma unroll
    for (int off = 32; off; off >>= 1) m = fmaxf(m, __shfl_xor(m, off));

    __shared__ float rm[4], rs[4];
    int wave = t >> 6, lane = t & 63;
    if (lane == 0) rm[wave] = m;
    __syncthreads();
    m = fmaxf(fmaxf(rm[0], rm[1]), fmaxf(rm[2], rm[3]));

    float e0 = __expf(v0 - m), e1 = __expf(v1 - m);
    float e2 = __expf(v2 - m), e3 = __expf(v3 - m);
    float s = e0 + e1 + e2 + e3;
#pragma unroll
    for (int off = 32; off; off >>= 1) s += __shfl_xor(s, off);
    if (lane == 0) rs[wave] = s;
    __syncthreads();
    s = rs[0] + rs[1] + rs[2] + rs[3];

    float inv = 1.0f / s;
    w.x = (unsigned int)f2bf(e0 * inv) | ((unsigned int)f2bf(e1 * inv) << 16);
    w.y = (unsigned int)f2bf(e2 * inv) | ((unsigned int)f2bf(e3 * inv) << 16);
    *(uint2*)(p + t * 4) = w;
}

// ---------------------------------------------------------------------------
// v_epi: D[c][n] = Wv[c][:] . xt[b][n][:] ; out = g*(D+bv[c])*att[b][n][c] + x
// ---------------------------------------------------------------------------
__global__ __launch_bounds__(256) void v_epi_mfma(
    const u16* __restrict__ Wvb, const float* __restrict__ bv,
    const u16* __restrict__ xt, const u16* __restrict__ att,
    const float* __restrict__ x, const float* __restrict__ gamma,
    float* __restrict__ out)
{
    int bid = blockIdx.x;              // b*64 + mt*8 + nt
    int b  = bid >> 6;
    int m0 = ((bid >> 3) & 7) * 128;
    int n0 = (bid & 7) * 128;

    __shared__ u16 As[128][56], Bs[128][56];
    const u16* Wb = Wvb + (size_t)m0 * C_;
    const u16* xb16 = xt + (size_t)b * N_ * C_ + (size_t)n0 * C_;

    int t = threadIdx.x, lane = t & 63, wid = t >> 6;
    int wm = wid >> 1, wn = wid & 1;
    int lm = lane & 15, l4 = lane >> 4, kg = l4 * 8;

    f32x4 acc[4][4] = {};
    for (int k0 = 0; k0 < C_; k0 += 32) {
        __syncthreads();
        stage_tile(Wb,   k0, C_, As, t);
        stage_tile(xb16, k0, C_, Bs, t);
        __syncthreads();
        MFMA_CORE(As, Bs, acc, wm, wn, lm, kg);
    }

    const u16* attb = att + (size_t)b * N_ * N_;
    const float* xb = x + (size_t)b * C_ * N_;
    float* ob = out + (size_t)b * C_ * N_;
    float g = gamma[0];

#pragma unroll
    for (int fi = 0; fi < 4; ++fi) {
        int cb = m0 + wm * 64 + fi * 16 + l4 * 4;
        float4 bv4 = *(const float4*)(bv + cb);
        float bvv[4] = {bv4.x, bv4.y, bv4.z, bv4.w};
#pragma unroll
        for (int fj = 0; fj < 4; ++fj) {
            int n = n0 + wn * 64 + fj * 16 + lm;
            const u16* ap = attb + (size_t)n * N_ + cb;
#pragma unroll
            for (int r = 0; r < 4; ++r) {
                float attv = bf2f(ap[r]);
                float vv = acc[fi][fj][r] + bvv[r];
                size_t off = (size_t)(cb + r) * N_ + n;
                ob[off] = g * vv * attv + xb[off];
            }
        }
    }
}

// ---------------------------------------------------------------------------
extern "C" void kernel_launch(void* const* d_in, const int* in_sizes, int n_in,
                              void* d_out, int out_size, void* d_ws, size_t ws_size,
                              hipStream_t stream)
{
    const float* x     = (const float*)d_in[0];
    const float* Wq    = (const float*)d_in[1];
    const float* bq    = (const float*)d_in[2];
    const float* Wk    = (const float*)d_in[3];
    const float* bk    = (const float*)d_in[4];
    const float* Wv    = (const float*)d_in[5];
    const float* bv    = (const float*)d_in[6];
    const float* gamma = (const float*)d_in[7];
    float* out = (float*)d_out;

    char* ws = (char*)d_ws;
    u16* xt  = (u16*)ws;                              // 64 MiB  [b][n][c] bf16
    u16* Qt  = (u16*)(ws + ((size_t)64  << 20));      //  8 MiB  [b][n][o]
    u16* Kt  = (u16*)(ws + ((size_t)72  << 20));      //  8 MiB
    u16* att = (u16*)(ws + ((size_t)80  << 20));      // 64 MiB  [b][n][m]
    u16* Wvb = (u16*)(ws + ((size_t)144 << 20));      //  2 MiB
    u16* Wqb = (u16*)(ws + ((size_t)146 << 20));      //  0.25 MiB
    u16* Wkb = (u16*)(ws + ((size_t)147 << 20));      //  0.25 MiB

    cvt_f32_bf16<<<1024, 256, 0, stream>>>(Wv, Wvb, C_ * C_);
    cvt_f32_bf16<<<128,  256, 0, stream>>>(Wq, Wqb, C8_ * C_);
    cvt_f32_bf16<<<128,  256, 0, stream>>>(Wk, Wkb, C8_ * C_);

    transpose_x<<<B_ * 256, 256, 0, stream>>>(x, xt);

    proj_mfma<<<B_ * 16, 256, 0, stream>>>(Wqb, Wkb, bq, bk, xt, Qt, Kt);
    energy_mfma<<<B_ * 64, 256, 0, stream>>>(Qt, Kt, att);
    softmax_bf16<<<B_ * N_, 256, 0, stream>>>(att);
    v_epi_mfma<<<B_ * 64, 256, 0, stream>>>(Wvb, bv, xt, att, x, gamma, out);
}